// Round 7
// baseline (3983.483 us; speedup 1.0000x reference)
//
#include <hip/hip_runtime.h>
#include <hip/hip_bf16.h>
#include <math.h>

#define NN 8192
#define DD 256
#define KSEED 5
#define CC 64
#define TK 8
#define NITERS 20
#define CSPLIT 8
#define BM 128
#define BN 128
#define BK2 32
#define UB 32  // kupd12 gather batch rows

__device__ __forceinline__ bool kbetter(float v1, int i1, float v2, int i2) {
    return (v1 > v2) || ((v1 == v2) && (i1 < i2));
}

// ---------------------------------------------------------------- transpose
// in [NN][DD] -> out [DD][NN]
__global__ __launch_bounds__(256) void transpose_k(const float* __restrict__ in,
                                                   float* __restrict__ out) {
    __shared__ float t[32][33];
    int bx = blockIdx.x * 32;  // N base
    int by = blockIdx.y * 32;  // D base
    int x = threadIdx.x;       // 0..31
    int y = threadIdx.y;       // 0..7
#pragma unroll
    for (int i = 0; i < 32; i += 8)
        t[y + i][x] = in[(size_t)(bx + y + i) * DD + by + x];
    __syncthreads();
#pragma unroll
    for (int i = 0; i < 32; i += 8)
        out[(size_t)(by + y + i) * NN + bx + x] = t[x][y + i];
}

// ---------------------------------------------------------------- adjacency bitmap
__global__ __launch_bounds__(256) void adj_k(const int* __restrict__ e0,
                                             const int* __restrict__ e1,
                                             unsigned int* __restrict__ bm, int E) {
    int t = blockIdx.x * 256 + threadIdx.x;
    if (t < E) {
        unsigned code = (unsigned)e0[t] * NN + (unsigned)e1[t];
        atomicOr(&bm[code >> 5], 1u << (code & 31));
    }
}

// ---------------------------------------------------------------- kmeans init
// centT layout: [s][d][c]
__global__ __launch_bounds__(256) void kinit_k(const float* __restrict__ teacher,
                                               const int* __restrict__ initIdx,
                                               float* __restrict__ centT,
                                               float* __restrict__ cnorm) {
    int c = blockIdx.x, s = blockIdx.y;
    int t = threadIdx.x;
    int src = initIdx[s * CC + c];
    float v = teacher[(size_t)src * DD + t];
    centT[((size_t)s * DD + t) * CC + c] = v;
    __shared__ float red[256];
    red[t] = v * v;
    __syncthreads();
    for (int w = 128; w > 0; w >>= 1) {
        if (t < w) red[t] += red[t + w];
        __syncthreads();
    }
    if (t == 0) cnorm[s * CC + c] = red[0];
}

// ---------------------------------------------------------------- kmeans assign
// 64 points x 64 clusters per block; 4x4 thread tile (16 acc regs).
// d2 = ||c||^2 - 2 x.c ; argmin over c (ties -> lowest c)
__global__ __launch_bounds__(256) void kassign_k(const float* __restrict__ tT,
                                                 const float* __restrict__ centT,
                                                 const float* __restrict__ cnorm,
                                                 int* __restrict__ labels) {
    __shared__ float Xs[64 * 64];  // [kk][pt] 16 KB
    __shared__ float Cs[64 * 64];  // [kk][c]  16 KB (reused for argmin reduce)
    const int s = blockIdx.y;
    const int pB = blockIdx.x * 64;
    const int tid = threadIdx.x;
    const int tx = tid & 15;   // cluster group: 4tx..4tx+3
    const int ty = tid >> 4;   // point group: 4ty..4ty+3
    float acc[4][4];
#pragma unroll
    for (int a = 0; a < 4; a++)
#pragma unroll
        for (int b = 0; b < 4; b++) acc[a][b] = 0.f;

    for (int kt = 0; kt < DD; kt += 64) {
        __syncthreads();
#pragma unroll
        for (int m = 0; m < 4; m++) {
            int u = m * 256 + tid;
            int kk = u >> 4;
            int p4 = (u & 15) << 2;
            *(float4*)&Xs[kk * 64 + p4] =
                *(const float4*)&tT[(size_t)(kt + kk) * NN + pB + p4];
            *(float4*)&Cs[kk * 64 + p4] =
                *(const float4*)&centT[((size_t)s * DD + kt + kk) * CC + p4];
        }
        __syncthreads();
#pragma unroll 8
        for (int kk = 0; kk < 64; kk++) {
            float4 x4 = *(float4*)&Xs[kk * 64 + 4 * ty];
            float4 c4 = *(float4*)&Cs[kk * 64 + 4 * tx];
            float xr[4] = {x4.x, x4.y, x4.z, x4.w};
            float cr[4] = {c4.x, c4.y, c4.z, c4.w};
#pragma unroll
            for (int a = 0; a < 4; a++)
#pragma unroll
                for (int b = 0; b < 4; b++) acc[a][b] = fmaf(xr[a], cr[b], acc[a][b]);
        }
    }
    __syncthreads();
    float* red = Cs;  // [64 pts][16 tx][2] = 2048 floats
    float cn[4];
#pragma unroll
    for (int b = 0; b < 4; b++) cn[b] = cnorm[s * CC + 4 * tx + b];
#pragma unroll
    for (int a = 0; a < 4; a++) {
        float bv = INFINITY;
        int bc = 0;
#pragma unroll
        for (int b = 0; b < 4; b++) {
            float d = fmaf(-2.f, acc[a][b], cn[b]);
            if (d < bv) { bv = d; bc = 4 * tx + b; }
        }
        int p = 4 * ty + a;
        red[(p * 16 + tx) * 2] = bv;
        ((int*)red)[(p * 16 + tx) * 2 + 1] = bc;
    }
    __syncthreads();
    if (tid < 64) {
        float bv = INFINITY;
        int bc = 0;
        for (int t2 = 0; t2 < 16; t2++) {  // ascending c -> lowest-c tie-break
            float v = red[(tid * 16 + t2) * 2];
            int c = ((int*)red)[(tid * 16 + t2) * 2 + 1];
            if (v < bv) { bv = v; bc = c; }
        }
        labels[(size_t)s * NN + pB + tid] = bc;
    }
}

// ---------------------------------------------------------------- fused kmeans update (upd1+upd2)
// One block per (c, s). Builds the ascending list of points with label c,
// then accumulates with the EXACT summation tree of the old kupd1/kupd2
// pair (per-256-chunk partial from 0.0f ascending i; chunk partials added
// ascending, empties add 0.0f) -> bitwise-identical centroids.
// Gather is batch-staged through LDS so global latency is parallel, not
// on the serial accumulate chain.
__global__ __launch_bounds__(256) void kupd12_k(const float* __restrict__ teacher,
                                                const int* __restrict__ labels,
                                                float* __restrict__ centT,
                                                float* __restrict__ cnorm) {
    const int c = blockIdx.x;
    const int s = blockIdx.y;
    const int t = threadIdx.x;
    __shared__ int list[NN];          // 32 KB: ascending matching point indices
    __shared__ float stage[UB * DD];  // 32 KB: gathered rows
    __shared__ int scan_s[256];
    __shared__ float red[256];
    __shared__ int total_s;

    const int* labS = labels + (size_t)s * NN;

    // count matches in this thread's 32-point stretch [32t, 32t+32)
    int my = 0;
#pragma unroll
    for (int j = 0; j < 32; j++) my += (labS[t * 32 + j] == c);
    scan_s[t] = my;
    __syncthreads();
    // inclusive prefix scan over 256 threads
    for (int off = 1; off < 256; off <<= 1) {
        int v = (t >= off) ? scan_s[t - off] : 0;
        __syncthreads();
        scan_s[t] += v;
        __syncthreads();
    }
    const int base = scan_s[t] - my;  // exclusive
    if (t == 255) total_s = scan_s[255];
    // ordered fill: stretches are ordered by t, within-stretch ascending
    int pos = base;
#pragma unroll
    for (int j = 0; j < 32; j++) {
        int p = t * 32 + j;
        if (labS[p] == c) list[pos++] = p;
    }
    __syncthreads();
    const int total = total_s;

    // batched gather + exact two-level tree sum
    float sum = 0.f, part = 0.f;
    int curb = 0;  // current 256-point chunk id (0..31)
    for (int g0 = 0; g0 < total; g0 += UB) {
        const int gn = (total - g0 < UB) ? (total - g0) : UB;
        __syncthreads();  // previous batch's stage reads complete
        // cooperative stage: rows list[g0..g0+gn) -> stage[j][*]; coalesced
        for (int u = t; u < gn * (DD / 4); u += 256) {
            int j = u >> 6;       // 64 float4 per row
            int col4 = (u & 63) << 2;
            *(float4*)&stage[j * DD + col4] =
                *(const float4*)&teacher[(size_t)list[g0 + j] * DD + col4];
        }
        __syncthreads();
        // ordered accumulate from LDS (uniform control flow, no global latency)
        for (int j = 0; j < gn; j++) {
            int p = list[g0 + j];  // LDS broadcast
            int b = p >> 8;
            while (curb < b) { sum += part; part = 0.f; curb++; }
            part += stage[j * DD + t];
        }
    }
    while (curb < 32) { sum += part; part = 0.f; curb++; }

    float old = centT[((size_t)s * DD + t) * CC + c];
    float nv = (total > 0) ? (sum / (float)total) : old;
    centT[((size_t)s * DD + t) * CC + c] = nv;
    red[t] = nv * nv;
    __syncthreads();
    for (int w = 128; w > 0; w >>= 1) {
        if (t < w) red[t] += red[t + w];
        __syncthreads();
    }
    if (t == 0) cnorm[s * CC + c] = red[0];
}

// ---------------------------------------------------------------- fused GEMM + per-row top-8 (per column split)
// Register-staged double-buffered pipeline: issue next k-slice's global
// loads at compute-phase start, ds_write after compute, one barrier per
// slice. NO min-waves clamp in launch_bounds (round-4's (256,2) forced a
// 128-VGPR cap -> spills); plain (256) allows ~220 VGPR, no spill, still
// 2 blocks/CU (64 KB LDS). K-chain per (row,col) bitwise-identical to the
// BK=64 version: k ascends 0..255 in the same fmaf order.
__global__ __launch_bounds__(256) void topk_gemm_k(const float* __restrict__ sT,
                                                   const float* __restrict__ tT,
                                                   float* __restrict__ pv,
                                                   int* __restrict__ pi) {
    __shared__ float smem[16384];  // 64 KB: 2 x (A 32x128 + B 32x128); reused for scan/merge

    const int split = blockIdx.x;
    const int rowB = blockIdx.y * BM;
    const int tid = threadIdx.x;
    const int tx = tid & 15;
    const int ty = tid >> 4;
    const int sr = tid >> 1;  // scan row 0..127
    const int sh = tid & 1;   // scan half

    // staging decomposition: m in 0..3 -> u = m*256+tid; kk = u>>5 (0..31);
    // r4 = (u&31)<<2  (lane-contiguous 16B, coalesced)
    const int skk[4] = {tid >> 5, (256 + tid) >> 5, (512 + tid) >> 5, (768 + tid) >> 5};
    const int sr4 = (tid & 31) << 2;

    float tv[TK];
    int ti[TK];
#pragma unroll
    for (int q = 0; q < TK; q++) { tv[q] = -INFINITY; ti[q] = 0x7fffffff; }

    const int colBase = split * (NN / CSPLIT);

    for (int ct = 0; ct < NN / CSPLIT; ct += BN) {
        const int colB = colBase + ct;
        float acc[8][8];
#pragma unroll
        for (int a = 0; a < 8; a++)
#pragma unroll
            for (int b = 0; b < 8; b++) acc[a][b] = 0.f;

        // prologue: stage slice kt=0 into buf0
        {
            float4 pa[4], pb[4];
#pragma unroll
            for (int m = 0; m < 4; m++) {
                pa[m] = *(const float4*)&sT[(size_t)skk[m] * NN + rowB + sr4];
                pb[m] = *(const float4*)&tT[(size_t)skk[m] * NN + colB + sr4];
            }
#pragma unroll
            for (int m = 0; m < 4; m++) {
                *(float4*)&smem[skk[m] * BM + sr4] = pa[m];
                *(float4*)&smem[4096 + skk[m] * BN + sr4] = pb[m];
            }
        }
        __syncthreads();

        for (int kt = 0; kt < DD; kt += BK2) {
            const int cur = (kt >> 5) & 1;
            float* bufn = smem + (cur ^ 1) * 8192;
            const float* As = smem + cur * 8192;
            const float* Bs = As + 4096;
            const bool more = (kt + BK2) < DD;

            // issue next slice's global loads NOW; latency hides under compute
            float4 pa[4], pb[4];
            if (more) {
#pragma unroll
                for (int m = 0; m < 4; m++) {
                    int krow = kt + BK2 + skk[m];
                    pa[m] = *(const float4*)&sT[(size_t)krow * NN + rowB + sr4];
                    pb[m] = *(const float4*)&tT[(size_t)krow * NN + colB + sr4];
                }
            }

#pragma unroll
            for (int kk = 0; kk < BK2; kk++) {
                float4 a0 = *(const float4*)&As[kk * BM + 4 * ty];
                float4 a1 = *(const float4*)&As[kk * BM + 64 + 4 * ty];
                float4 b0 = *(const float4*)&Bs[kk * BN + 4 * tx];
                float4 b1 = *(const float4*)&Bs[kk * BN + 64 + 4 * tx];
                float ar[8] = {a0.x, a0.y, a0.z, a0.w, a1.x, a1.y, a1.z, a1.w};
                float bc[8] = {b0.x, b0.y, b0.z, b0.w, b1.x, b1.y, b1.z, b1.w};
#pragma unroll
                for (int a = 0; a < 8; a++)
#pragma unroll
                    for (int b = 0; b < 8; b++)
                        acc[a][b] = fmaf(ar[a], bc[b], acc[a][b]);
            }

            if (more) {
#pragma unroll
                for (int m = 0; m < 4; m++) {
                    *(float4*)&bufn[skk[m] * BM + sr4] = pa[m];
                    *(float4*)&bufn[4096 + skk[m] * BN + sr4] = pb[m];
                }
            }
            __syncthreads();
        }

        // stage tile to LDS with XOR bank swizzle (+ diagonal boost)
#pragma unroll
        for (int a = 0; a < 8; a++) {
            int ra = (a < 4) ? (4 * ty + a) : (64 + 4 * ty + (a - 4));
            int grow = rowB + ra;
#pragma unroll
            for (int b = 0; b < 8; b++) {
                int cb = (b < 4) ? (4 * tx + b) : (64 + 4 * tx + (b - 4));
                float v = acc[a][b];
                if (grow == colB + cb) v += 10.f;
                smem[ra * BM + (cb ^ (ra & 31))] = v;
            }
        }
        __syncthreads();
        // per-thread running top-8 over this tile's 64 columns
#pragma unroll 4
        for (int c = 0; c < 64; c++) {
            int cb = sh * 64 + c;
            float v = smem[sr * BM + (cb ^ (sr & 31))];
            int gcol = colB + cb;
            if (kbetter(v, gcol, tv[TK - 1], ti[TK - 1])) {
                tv[TK - 1] = v;
                ti[TK - 1] = gcol;
#pragma unroll
                for (int q = TK - 1; q > 0; --q) {
                    if (kbetter(tv[q], ti[q], tv[q - 1], ti[q - 1])) {
                        float t1 = tv[q]; tv[q] = tv[q - 1]; tv[q - 1] = t1;
                        int t2 = ti[q]; ti[q] = ti[q - 1]; ti[q - 1] = t2;
                    }
                }
            }
        }
        __syncthreads();  // scan reads done before next ct's prologue ds_write
    }
    // merge the two halves of each row, write split-partial top-8
    float* mv = smem;                  // [128][2][8]
    int* mi = (int*)(smem + 2048);     // [128][2][8]
#pragma unroll
    for (int q = 0; q < TK; q++) {
        mv[(sr * 2 + sh) * TK + q] = tv[q];
        mi[(sr * 2 + sh) * TK + q] = ti[q];
    }
    __syncthreads();
    if (sh == 0) {
        int row = rowB + sr;
        unsigned used = 0;
        for (int o = 0; o < TK; o++) {
            float bv = -INFINITY;
            int bi = 0x7fffffff;
            int bsel = -1;
            for (int m = 0; m < 16; m++) {
                if ((used >> m) & 1u) continue;
                float v = mv[sr * 16 + m];
                int ix = mi[sr * 16 + m];
                if (bsel < 0 || kbetter(v, ix, bv, bi)) { bv = v; bi = ix; bsel = m; }
            }
            used |= 1u << bsel;
            pv[((size_t)row * CSPLIT + split) * TK + o] = bv;
            pi[((size_t)row * CSPLIT + split) * TK + o] = bi;
        }
    }
}

// ---------------------------------------------------------------- merge split partials -> final top-8
__global__ __launch_bounds__(256) void topk_merge_k(const float* __restrict__ pv,
                                                    const int* __restrict__ pi,
                                                    int* __restrict__ iknn,
                                                    float* __restrict__ dknn) {
    int row = blockIdx.x * 256 + threadIdx.x;
    if (row >= NN) return;
    unsigned long long used = 0;
    for (int o = 0; o < TK; o++) {
        float bv = -INFINITY;
        int bi = 0x7fffffff;
        int bsel = -1;
        for (int m = 0; m < CSPLIT * TK; m++) {
            if ((used >> m) & 1ull) continue;
            float v = pv[(size_t)row * CSPLIT * TK + m];
            int ix = pi[(size_t)row * CSPLIT * TK + m];
            if (bsel < 0 || kbetter(v, ix, bv, bi)) { bv = v; bi = ix; bsel = m; }
        }
        used |= 1ull << bsel;
        iknn[row * TK + o] = bi;
        dknn[row * TK + o] = bv;
    }
}

// ---------------------------------------------------------------- epilogue: masks + output
__global__ __launch_bounds__(256) void out_k(const int* __restrict__ iknn,
                                             const float* __restrict__ dknn,
                                             const unsigned int* __restrict__ bm,
                                             const int* __restrict__ labels,
                                             float* __restrict__ out) {
    int t = blockIdx.x * 256 + threadIdx.x;  // 0..65535
    int row = t >> 3;
    int ki = iknn[t];
    unsigned code = (unsigned)row * NN + (unsigned)ki;
    bool adj = (bm[code >> 5] >> (code & 31)) & 1u;
    bool close = false;
#pragma unroll
    for (int s = 0; s < KSEED; s++)
        close |= (labels[s * NN + row] == labels[s * NN + ki]);
    out[t] = (float)ki;
    out[NN * TK + t] = (adj || close) ? 1.0f : 0.0f;
    out[2 * NN * TK + t] = dknn[t];
}

// ----------------------------------------------------------------
extern "C" void kernel_launch(void* const* d_in, const int* in_sizes, int n_in,
                              void* d_out, int out_size, void* d_ws, size_t ws_size,
                              hipStream_t stream) {
    (void)n_in; (void)out_size; (void)ws_size;
    const float* student = (const float*)d_in[0];
    const float* teacher = (const float*)d_in[1];
    const int* edge = (const int*)d_in[2];
    const int* initIdx = (const int*)d_in[3];
    const int E = in_sizes[2] / 2;

    char* ws = (char*)d_ws;
    size_t off = 0;
    auto alloc = [&](size_t bytes) -> char* {
        char* p = ws + off;
        off += (bytes + 255) & ~(size_t)255;
        return p;
    };
    unsigned int* bm = (unsigned int*)alloc((size_t)NN * NN / 8);        // 8 MB
    float* sT = (float*)alloc((size_t)NN * DD * 4);                      // 8 MB
    float* tT = (float*)alloc((size_t)NN * DD * 4);                      // 8 MB
    float* centT = (float*)alloc((size_t)KSEED * DD * CC * 4);
    float* cnorm = (float*)alloc((size_t)KSEED * CC * 4);
    int* labels = (int*)alloc((size_t)KSEED * NN * 4);
    float* pv = (float*)alloc((size_t)NN * CSPLIT * TK * 4);
    int* pi = (int*)alloc((size_t)NN * CSPLIT * TK * 4);
    int* iknn = (int*)alloc((size_t)NN * TK * 4);
    float* dknn = (float*)alloc((size_t)NN * TK * 4);
    float* out = (float*)d_out;

    hipMemsetAsync(bm, 0, (size_t)NN * NN / 8, stream);
    adj_k<<<dim3((E + 255) / 256), 256, 0, stream>>>(edge, edge + E, bm, E);
    transpose_k<<<dim3(NN / 32, DD / 32), dim3(32, 8), 0, stream>>>(student, sT);
    transpose_k<<<dim3(NN / 32, DD / 32), dim3(32, 8), 0, stream>>>(teacher, tT);

    kinit_k<<<dim3(CC, KSEED), 256, 0, stream>>>(teacher, initIdx, centT, cnorm);
    for (int it = 0; it < NITERS; ++it) {
        kassign_k<<<dim3(NN / 64, KSEED), 256, 0, stream>>>(tT, centT, cnorm, labels);
        kupd12_k<<<dim3(CC, KSEED), 256, 0, stream>>>(teacher, labels, centT, cnorm);
    }
    kassign_k<<<dim3(NN / 64, KSEED), 256, 0, stream>>>(tT, centT, cnorm, labels);

    topk_gemm_k<<<dim3(CSPLIT, NN / BM), 256, 0, stream>>>(sT, tT, pv, pi);
    topk_merge_k<<<dim3((NN + 255) / 256), 256, 0, stream>>>(pv, pi, iknn, dknn);
    out_k<<<dim3(NN * TK / 256), 256, 0, stream>>>(iknn, dknn, bm, labels, out);
}

// Round 8
// 2744.452 us; speedup vs baseline: 1.4515x; 1.4515x over previous
//
#include <hip/hip_runtime.h>
#include <hip/hip_bf16.h>
#include <math.h>

#define NN 8192
#define DD 256
#define KSEED 5
#define CC 64
#define TK 8
#define NITERS 20
#define CSPLIT 16
#define BM 128
#define BN 128
#define BK 32
#define UB 32  // kupd12 gather batch rows

__device__ __forceinline__ bool kbetter(float v1, int i1, float v2, int i2) {
    return (v1 > v2) || ((v1 == v2) && (i1 < i2));
}

// ---------------------------------------------------------------- transpose
// in [NN][DD] -> out [DD][NN]
__global__ __launch_bounds__(256) void transpose_k(const float* __restrict__ in,
                                                   float* __restrict__ out) {
    __shared__ float t[32][33];
    int bx = blockIdx.x * 32;  // N base
    int by = blockIdx.y * 32;  // D base
    int x = threadIdx.x;       // 0..31
    int y = threadIdx.y;       // 0..7
#pragma unroll
    for (int i = 0; i < 32; i += 8)
        t[y + i][x] = in[(size_t)(bx + y + i) * DD + by + x];
    __syncthreads();
#pragma unroll
    for (int i = 0; i < 32; i += 8)
        out[(size_t)(by + y + i) * NN + bx + x] = t[x][y + i];
}

// ---------------------------------------------------------------- adjacency bitmap
__global__ __launch_bounds__(256) void adj_k(const int* __restrict__ e0,
                                             const int* __restrict__ e1,
                                             unsigned int* __restrict__ bm, int E) {
    int t = blockIdx.x * 256 + threadIdx.x;
    if (t < E) {
        unsigned code = (unsigned)e0[t] * NN + (unsigned)e1[t];
        atomicOr(&bm[code >> 5], 1u << (code & 31));
    }
}

// ---------------------------------------------------------------- kmeans init
// centT layout: [s][d][c]
__global__ __launch_bounds__(256) void kinit_k(const float* __restrict__ teacher,
                                               const int* __restrict__ initIdx,
                                               float* __restrict__ centT,
                                               float* __restrict__ cnorm) {
    int c = blockIdx.x, s = blockIdx.y;
    int t = threadIdx.x;
    int src = initIdx[s * CC + c];
    float v = teacher[(size_t)src * DD + t];
    centT[((size_t)s * DD + t) * CC + c] = v;
    __shared__ float red[256];
    red[t] = v * v;
    __syncthreads();
    for (int w = 128; w > 0; w >>= 1) {
        if (t < w) red[t] += red[t + w];
        __syncthreads();
    }
    if (t == 0) cnorm[s * CC + c] = red[0];
}

// ---------------------------------------------------------------- kmeans assign
// 64 points x 64 clusters per block; 4x4 thread tile (16 acc regs).
// d2 = ||c||^2 - 2 x.c ; argmin over c (ties -> lowest c)
__global__ __launch_bounds__(256) void kassign_k(const float* __restrict__ tT,
                                                 const float* __restrict__ centT,
                                                 const float* __restrict__ cnorm,
                                                 int* __restrict__ labels) {
    __shared__ float Xs[64 * 64];  // [kk][pt] 16 KB
    __shared__ float Cs[64 * 64];  // [kk][c]  16 KB (reused for argmin reduce)
    const int s = blockIdx.y;
    const int pB = blockIdx.x * 64;
    const int tid = threadIdx.x;
    const int tx = tid & 15;   // cluster group: 4tx..4tx+3
    const int ty = tid >> 4;   // point group: 4ty..4ty+3
    float acc[4][4];
#pragma unroll
    for (int a = 0; a < 4; a++)
#pragma unroll
        for (int b = 0; b < 4; b++) acc[a][b] = 0.f;

    for (int kt = 0; kt < DD; kt += 64) {
        __syncthreads();
#pragma unroll
        for (int m = 0; m < 4; m++) {
            int u = m * 256 + tid;
            int kk = u >> 4;
            int p4 = (u & 15) << 2;
            *(float4*)&Xs[kk * 64 + p4] =
                *(const float4*)&tT[(size_t)(kt + kk) * NN + pB + p4];
            *(float4*)&Cs[kk * 64 + p4] =
                *(const float4*)&centT[((size_t)s * DD + kt + kk) * CC + p4];
        }
        __syncthreads();
#pragma unroll 8
        for (int kk = 0; kk < 64; kk++) {
            float4 x4 = *(float4*)&Xs[kk * 64 + 4 * ty];
            float4 c4 = *(float4*)&Cs[kk * 64 + 4 * tx];
            float xr[4] = {x4.x, x4.y, x4.z, x4.w};
            float cr[4] = {c4.x, c4.y, c4.z, c4.w};
#pragma unroll
            for (int a = 0; a < 4; a++)
#pragma unroll
                for (int b = 0; b < 4; b++) acc[a][b] = fmaf(xr[a], cr[b], acc[a][b]);
        }
    }
    __syncthreads();
    float* red = Cs;  // [64 pts][16 tx][2] = 2048 floats
    float cn[4];
#pragma unroll
    for (int b = 0; b < 4; b++) cn[b] = cnorm[s * CC + 4 * tx + b];
#pragma unroll
    for (int a = 0; a < 4; a++) {
        float bv = INFINITY;
        int bc = 0;
#pragma unroll
        for (int b = 0; b < 4; b++) {
            float d = fmaf(-2.f, acc[a][b], cn[b]);
            if (d < bv) { bv = d; bc = 4 * tx + b; }
        }
        int p = 4 * ty + a;
        red[(p * 16 + tx) * 2] = bv;
        ((int*)red)[(p * 16 + tx) * 2 + 1] = bc;
    }
    __syncthreads();
    if (tid < 64) {
        float bv = INFINITY;
        int bc = 0;
        for (int t2 = 0; t2 < 16; t2++) {  // ascending c -> lowest-c tie-break
            float v = red[(tid * 16 + t2) * 2];
            int c = ((int*)red)[(tid * 16 + t2) * 2 + 1];
            if (v < bv) { bv = v; bc = c; }
        }
        labels[(size_t)s * NN + pB + tid] = bc;
    }
}

// ---------------------------------------------------------------- fused kmeans update (upd1+upd2)
// One block per (c, s). Builds the ascending list of points with label c,
// then accumulates with the EXACT summation tree of the old kupd1/kupd2
// pair (per-256-chunk partial from 0.0f ascending i; chunk partials added
// ascending, empties add 0.0f) -> bitwise-identical centroids.
// Gather is batch-staged through LDS so global latency is parallel, not
// on the serial accumulate chain.
__global__ __launch_bounds__(256) void kupd12_k(const float* __restrict__ teacher,
                                                const int* __restrict__ labels,
                                                float* __restrict__ centT,
                                                float* __restrict__ cnorm) {
    const int c = blockIdx.x;
    const int s = blockIdx.y;
    const int t = threadIdx.x;
    __shared__ int list[NN];          // 32 KB: ascending matching point indices
    __shared__ float stage[UB * DD];  // 32 KB: gathered rows
    __shared__ int scan_s[256];
    __shared__ float red[256];
    __shared__ int total_s;

    const int* labS = labels + (size_t)s * NN;

    // count matches in this thread's 32-point stretch [32t, 32t+32)
    int my = 0;
#pragma unroll
    for (int j = 0; j < 32; j++) my += (labS[t * 32 + j] == c);
    scan_s[t] = my;
    __syncthreads();
    // inclusive prefix scan over 256 threads
    for (int off = 1; off < 256; off <<= 1) {
        int v = (t >= off) ? scan_s[t - off] : 0;
        __syncthreads();
        scan_s[t] += v;
        __syncthreads();
    }
    const int base = scan_s[t] - my;  // exclusive
    if (t == 255) total_s = scan_s[255];
    // ordered fill: stretches are ordered by t, within-stretch ascending
    int pos = base;
#pragma unroll
    for (int j = 0; j < 32; j++) {
        int p = t * 32 + j;
        if (labS[p] == c) list[pos++] = p;
    }
    __syncthreads();
    const int total = total_s;

    // batched gather + exact two-level tree sum
    float sum = 0.f, part = 0.f;
    int curb = 0;  // current 256-point chunk id (0..31)
    for (int g0 = 0; g0 < total; g0 += UB) {
        const int gn = (total - g0 < UB) ? (total - g0) : UB;
        __syncthreads();  // previous batch's stage reads complete
        // cooperative stage: rows list[g0..g0+gn) -> stage[j][*]; coalesced
        for (int u = t; u < gn * (DD / 4); u += 256) {
            int j = u >> 6;       // 64 float4 per row
            int col4 = (u & 63) << 2;
            *(float4*)&stage[j * DD + col4] =
                *(const float4*)&teacher[(size_t)list[g0 + j] * DD + col4];
        }
        __syncthreads();
        // ordered accumulate from LDS (uniform control flow, no global latency)
        for (int j = 0; j < gn; j++) {
            int p = list[g0 + j];  // LDS broadcast
            int b = p >> 8;
            while (curb < b) { sum += part; part = 0.f; curb++; }
            part += stage[j * DD + t];
        }
    }
    while (curb < 32) { sum += part; part = 0.f; curb++; }

    float old = centT[((size_t)s * DD + t) * CC + c];
    float nv = (total > 0) ? (sum / (float)total) : old;
    centT[((size_t)s * DD + t) * CC + c] = nv;
    red[t] = nv * nv;
    __syncthreads();
    for (int w = 128; w > 0; w >>= 1) {
        if (t < w) red[t] += red[t + w];
        __syncthreads();
    }
    if (t == 0) cnorm[s * CC + c] = red[0];
}

// ---------------------------------------------------------------- fused GEMM + per-row top-8 (per column split)
// BK=32 single-buffered (32 KB LDS -> 4 blocks/CU with CSPLIT=16 grid):
// block-level TLP hides the staging stall instead of register prefetch
// (rounds 4/7 proved reg-prefetch spills). FMA chain per (row,col) still
// ascends k=0..255 in identical order -> bitwise-identical sums. C-scan
// runs in two 128x64 halves (top-8 of a partition union == true top-8
// under the strict kbetter order), so pv/pi are bitwise identical.
__global__ __launch_bounds__(256) void topk_gemm_k(const float* __restrict__ sT,
                                                   const float* __restrict__ tT,
                                                   float* __restrict__ pv,
                                                   int* __restrict__ pi) {
    __shared__ float smem[BK * BM + BK * BN];  // 32 KB, multi-purpose
    float* As = smem;            // [BK][BM] k-major
    float* Bs = smem + BK * BM;  // [BK][BN]

    const int split = blockIdx.x;
    const int rowB = blockIdx.y * BM;
    const int tid = threadIdx.x;
    const int tx = tid & 15;
    const int ty = tid >> 4;
    const int sr = tid >> 1;  // scan row 0..127
    const int sh = tid & 1;   // scan half-of-64-cols

    float tv[TK];
    int ti[TK];
#pragma unroll
    for (int q = 0; q < TK; q++) { tv[q] = -INFINITY; ti[q] = 0x7fffffff; }

    const int colBase = split * (NN / CSPLIT);

    for (int ct = 0; ct < NN / CSPLIT; ct += BN) {
        const int colB = colBase + ct;
        float acc[8][8];
#pragma unroll
        for (int a = 0; a < 8; a++)
#pragma unroll
            for (int b = 0; b < 8; b++) acc[a][b] = 0.f;

        for (int kt = 0; kt < DD; kt += BK) {
            __syncthreads();
#pragma unroll
            for (int m = 0; m < 4; m++) {
                int u = m * 256 + tid;
                int kk = u >> 5;
                int r4 = (u & 31) << 2;
                *(float4*)&As[kk * BM + r4] =
                    *(const float4*)&sT[(size_t)(kt + kk) * NN + rowB + r4];
                *(float4*)&Bs[kk * BN + r4] =
                    *(const float4*)&tT[(size_t)(kt + kk) * NN + colB + r4];
            }
            __syncthreads();
#pragma unroll
            for (int kk = 0; kk < BK; kk++) {
                float4 a0 = *(float4*)&As[kk * BM + 4 * ty];
                float4 a1 = *(float4*)&As[kk * BM + 64 + 4 * ty];
                float4 b0 = *(float4*)&Bs[kk * BN + 4 * tx];
                float4 b1 = *(float4*)&Bs[kk * BN + 64 + 4 * tx];
                float ar[8] = {a0.x, a0.y, a0.z, a0.w, a1.x, a1.y, a1.z, a1.w};
                float bc[8] = {b0.x, b0.y, b0.z, b0.w, b1.x, b1.y, b1.z, b1.w};
#pragma unroll
                for (int a = 0; a < 8; a++)
#pragma unroll
                    for (int b = 0; b < 8; b++)
                        acc[a][b] = fmaf(ar[a], bc[b], acc[a][b]);
            }
        }
        __syncthreads();
        // C-tile in two 128x64 halves: stage (swizzled, +diag) then scan
#pragma unroll
        for (int h = 0; h < 2; h++) {
#pragma unroll
            for (int a = 0; a < 8; a++) {
                int ra = (a < 4) ? (4 * ty + a) : (64 + 4 * ty + (a - 4));
                int grow = rowB + ra;
#pragma unroll
                for (int b2 = 0; b2 < 4; b2++) {
                    int cb2 = 4 * tx + b2;  // col within half (0..63)
                    float v = acc[a][h * 4 + b2];
                    if (grow == colB + h * 64 + cb2) v += 10.f;
                    smem[ra * 64 + (cb2 ^ (ra & 31))] = v;
                }
            }
            __syncthreads();
            // per-thread running top-8 over 32 of this half's 64 columns
#pragma unroll 4
            for (int c = 0; c < 32; c++) {
                int cb2 = sh * 32 + c;
                float v = smem[sr * 64 + (cb2 ^ (sr & 31))];
                int gcol = colB + h * 64 + cb2;
                if (kbetter(v, gcol, tv[TK - 1], ti[TK - 1])) {
                    tv[TK - 1] = v;
                    ti[TK - 1] = gcol;
#pragma unroll
                    for (int q = TK - 1; q > 0; --q) {
                        if (kbetter(tv[q], ti[q], tv[q - 1], ti[q - 1])) {
                            float t1 = tv[q]; tv[q] = tv[q - 1]; tv[q - 1] = t1;
                            int t2 = ti[q]; ti[q] = ti[q - 1]; ti[q - 1] = t2;
                        }
                    }
                }
            }
            __syncthreads();
        }
    }
    // merge the two threads of each row, write split-partial top-8
    float* mv = smem;                  // [128][2][8]
    int* mi = (int*)(smem + 2048);     // [128][2][8]
#pragma unroll
    for (int q = 0; q < TK; q++) {
        mv[(sr * 2 + sh) * TK + q] = tv[q];
        mi[(sr * 2 + sh) * TK + q] = ti[q];
    }
    __syncthreads();
    if (sh == 0) {
        int row = rowB + sr;
        unsigned used = 0;
        for (int o = 0; o < TK; o++) {
            float bv = -INFINITY;
            int bi = 0x7fffffff;
            int bsel = -1;
            for (int m = 0; m < 16; m++) {
                if ((used >> m) & 1u) continue;
                float v = mv[sr * 16 + m];
                int ix = mi[sr * 16 + m];
                if (bsel < 0 || kbetter(v, ix, bv, bi)) { bv = v; bi = ix; bsel = m; }
            }
            used |= 1u << bsel;
            pv[((size_t)row * CSPLIT + split) * TK + o] = bv;
            pi[((size_t)row * CSPLIT + split) * TK + o] = bi;
        }
    }
}

// ---------------------------------------------------------------- merge split partials -> final top-8
__global__ __launch_bounds__(256) void topk_merge_k(const float* __restrict__ pv,
                                                    const int* __restrict__ pi,
                                                    int* __restrict__ iknn,
                                                    float* __restrict__ dknn) {
    int row = blockIdx.x * 256 + threadIdx.x;
    if (row >= NN) return;
    unsigned long long used0 = 0, used1 = 0;  // CSPLIT*TK = 128 candidate slots
    for (int o = 0; o < TK; o++) {
        float bv = -INFINITY;
        int bi = 0x7fffffff;
        int bsel = -1;
        for (int m = 0; m < CSPLIT * TK; m++) {
            bool u = (m < 64) ? ((used0 >> m) & 1ull) : ((used1 >> (m - 64)) & 1ull);
            if (u) continue;
            float v = pv[(size_t)row * CSPLIT * TK + m];
            int ix = pi[(size_t)row * CSPLIT * TK + m];
            if (bsel < 0 || kbetter(v, ix, bv, bi)) { bv = v; bi = ix; bsel = m; }
        }
        if (bsel < 64) used0 |= 1ull << bsel; else used1 |= 1ull << (bsel - 64);
        iknn[row * TK + o] = bi;
        dknn[row * TK + o] = bv;
    }
}

// ---------------------------------------------------------------- epilogue: masks + output
__global__ __launch_bounds__(256) void out_k(const int* __restrict__ iknn,
                                             const float* __restrict__ dknn,
                                             const unsigned int* __restrict__ bm,
                                             const int* __restrict__ labels,
                                             float* __restrict__ out) {
    int t = blockIdx.x * 256 + threadIdx.x;  // 0..65535
    int row = t >> 3;
    int ki = iknn[t];
    unsigned code = (unsigned)row * NN + (unsigned)ki;
    bool adj = (bm[code >> 5] >> (code & 31)) & 1u;
    bool close = false;
#pragma unroll
    for (int s = 0; s < KSEED; s++)
        close |= (labels[s * NN + row] == labels[s * NN + ki]);
    out[t] = (float)ki;
    out[NN * TK + t] = (adj || close) ? 1.0f : 0.0f;
    out[2 * NN * TK + t] = dknn[t];
}

// ----------------------------------------------------------------
extern "C" void kernel_launch(void* const* d_in, const int* in_sizes, int n_in,
                              void* d_out, int out_size, void* d_ws, size_t ws_size,
                              hipStream_t stream) {
    (void)n_in; (void)out_size; (void)ws_size;
    const float* student = (const float*)d_in[0];
    const float* teacher = (const float*)d_in[1];
    const int* edge = (const int*)d_in[2];
    const int* initIdx = (const int*)d_in[3];
    const int E = in_sizes[2] / 2;

    char* ws = (char*)d_ws;
    size_t off = 0;
    auto alloc = [&](size_t bytes) -> char* {
        char* p = ws + off;
        off += (bytes + 255) & ~(size_t)255;
        return p;
    };
    unsigned int* bm = (unsigned int*)alloc((size_t)NN * NN / 8);        // 8 MB
    float* sT = (float*)alloc((size_t)NN * DD * 4);                      // 8 MB
    float* tT = (float*)alloc((size_t)NN * DD * 4);                      // 8 MB
    float* centT = (float*)alloc((size_t)KSEED * DD * CC * 4);
    float* cnorm = (float*)alloc((size_t)KSEED * CC * 4);
    int* labels = (int*)alloc((size_t)KSEED * NN * 4);
    float* pv = (float*)alloc((size_t)NN * CSPLIT * TK * 4);
    int* pi = (int*)alloc((size_t)NN * CSPLIT * TK * 4);
    int* iknn = (int*)alloc((size_t)NN * TK * 4);
    float* dknn = (float*)alloc((size_t)NN * TK * 4);
    float* out = (float*)d_out;

    hipMemsetAsync(bm, 0, (size_t)NN * NN / 8, stream);
    adj_k<<<dim3((E + 255) / 256), 256, 0, stream>>>(edge, edge + E, bm, E);
    transpose_k<<<dim3(NN / 32, DD / 32), dim3(32, 8), 0, stream>>>(student, sT);
    transpose_k<<<dim3(NN / 32, DD / 32), dim3(32, 8), 0, stream>>>(teacher, tT);

    kinit_k<<<dim3(CC, KSEED), 256, 0, stream>>>(teacher, initIdx, centT, cnorm);
    for (int it = 0; it < NITERS; ++it) {
        kassign_k<<<dim3(NN / 64, KSEED), 256, 0, stream>>>(tT, centT, cnorm, labels);
        kupd12_k<<<dim3(CC, KSEED), 256, 0, stream>>>(teacher, labels, centT, cnorm);
    }
    kassign_k<<<dim3(NN / 64, KSEED), 256, 0, stream>>>(tT, centT, cnorm, labels);

    topk_gemm_k<<<dim3(CSPLIT, NN / BM), 256, 0, stream>>>(sT, tT, pv, pi);
    topk_merge_k<<<dim3((NN + 255) / 256), 256, 0, stream>>>(pv, pi, iknn, dknn);
    out_k<<<dim3(NN * TK / 256), 256, 0, stream>>>(iknn, dknn, bm, labels, out);
}

// Round 9
// 2436.660 us; speedup vs baseline: 1.6348x; 1.1263x over previous
//
#include <hip/hip_runtime.h>
#include <hip/hip_bf16.h>
#include <math.h>

#define NN 8192
#define DD 256
#define KSEED 5
#define CC 64
#define TK 8
#define NITERS 20
#define CSPLIT 16
#define BM 128
#define BN 128
#define BK 32
#define UB 32  // kupd12 gather batch rows

__device__ __forceinline__ bool kbetter(float v1, int i1, float v2, int i2) {
    return (v1 > v2) || ((v1 == v2) && (i1 < i2));
}

// ---------------------------------------------------------------- transpose
// in [NN][DD] -> out [DD][NN]
__global__ __launch_bounds__(256) void transpose_k(const float* __restrict__ in,
                                                   float* __restrict__ out) {
    __shared__ float t[32][33];
    int bx = blockIdx.x * 32;  // N base
    int by = blockIdx.y * 32;  // D base
    int x = threadIdx.x;       // 0..31
    int y = threadIdx.y;       // 0..7
#pragma unroll
    for (int i = 0; i < 32; i += 8)
        t[y + i][x] = in[(size_t)(bx + y + i) * DD + by + x];
    __syncthreads();
#pragma unroll
    for (int i = 0; i < 32; i += 8)
        out[(size_t)(by + y + i) * NN + bx + x] = t[x][y + i];
}

// ---------------------------------------------------------------- adjacency bitmap
__global__ __launch_bounds__(256) void adj_k(const int* __restrict__ e0,
                                             const int* __restrict__ e1,
                                             unsigned int* __restrict__ bm, int E) {
    int t = blockIdx.x * 256 + threadIdx.x;
    if (t < E) {
        unsigned code = (unsigned)e0[t] * NN + (unsigned)e1[t];
        atomicOr(&bm[code >> 5], 1u << (code & 31));
    }
}

// ---------------------------------------------------------------- kmeans init
// centT layout: [s][d][c]
__global__ __launch_bounds__(256) void kinit_k(const float* __restrict__ teacher,
                                               const int* __restrict__ initIdx,
                                               float* __restrict__ centT,
                                               float* __restrict__ cnorm) {
    int c = blockIdx.x, s = blockIdx.y;
    int t = threadIdx.x;
    int src = initIdx[s * CC + c];
    float v = teacher[(size_t)src * DD + t];
    centT[((size_t)s * DD + t) * CC + c] = v;
    __shared__ float red[256];
    red[t] = v * v;
    __syncthreads();
    for (int w = 128; w > 0; w >>= 1) {
        if (t < w) red[t] += red[t + w];
        __syncthreads();
    }
    if (t == 0) cnorm[s * CC + c] = red[0];
}

// ---------------------------------------------------------------- kmeans assign
// 64 points x 64 clusters per block; 4x4 thread tile (16 acc regs).
// d2 = ||c||^2 - 2 x.c ; argmin over c (ties -> lowest c)
__global__ __launch_bounds__(256) void kassign_k(const float* __restrict__ tT,
                                                 const float* __restrict__ centT,
                                                 const float* __restrict__ cnorm,
                                                 int* __restrict__ labels) {
    __shared__ float Xs[64 * 64];  // [kk][pt] 16 KB
    __shared__ float Cs[64 * 64];  // [kk][c]  16 KB (reused for argmin reduce)
    const int s = blockIdx.y;
    const int pB = blockIdx.x * 64;
    const int tid = threadIdx.x;
    const int tx = tid & 15;   // cluster group: 4tx..4tx+3
    const int ty = tid >> 4;   // point group: 4ty..4ty+3
    float acc[4][4];
#pragma unroll
    for (int a = 0; a < 4; a++)
#pragma unroll
        for (int b = 0; b < 4; b++) acc[a][b] = 0.f;

    for (int kt = 0; kt < DD; kt += 64) {
        __syncthreads();
#pragma unroll
        for (int m = 0; m < 4; m++) {
            int u = m * 256 + tid;
            int kk = u >> 4;
            int p4 = (u & 15) << 2;
            *(float4*)&Xs[kk * 64 + p4] =
                *(const float4*)&tT[(size_t)(kt + kk) * NN + pB + p4];
            *(float4*)&Cs[kk * 64 + p4] =
                *(const float4*)&centT[((size_t)s * DD + kt + kk) * CC + p4];
        }
        __syncthreads();
#pragma unroll 8
        for (int kk = 0; kk < 64; kk++) {
            float4 x4 = *(float4*)&Xs[kk * 64 + 4 * ty];
            float4 c4 = *(float4*)&Cs[kk * 64 + 4 * tx];
            float xr[4] = {x4.x, x4.y, x4.z, x4.w};
            float cr[4] = {c4.x, c4.y, c4.z, c4.w};
#pragma unroll
            for (int a = 0; a < 4; a++)
#pragma unroll
                for (int b = 0; b < 4; b++) acc[a][b] = fmaf(xr[a], cr[b], acc[a][b]);
        }
    }
    __syncthreads();
    float* red = Cs;  // [64 pts][16 tx][2] = 2048 floats
    float cn[4];
#pragma unroll
    for (int b = 0; b < 4; b++) cn[b] = cnorm[s * CC + 4 * tx + b];
#pragma unroll
    for (int a = 0; a < 4; a++) {
        float bv = INFINITY;
        int bc = 0;
#pragma unroll
        for (int b = 0; b < 4; b++) {
            float d = fmaf(-2.f, acc[a][b], cn[b]);
            if (d < bv) { bv = d; bc = 4 * tx + b; }
        }
        int p = 4 * ty + a;
        red[(p * 16 + tx) * 2] = bv;
        ((int*)red)[(p * 16 + tx) * 2 + 1] = bc;
    }
    __syncthreads();
    if (tid < 64) {
        float bv = INFINITY;
        int bc = 0;
        for (int t2 = 0; t2 < 16; t2++) {  // ascending c -> lowest-c tie-break
            float v = red[(tid * 16 + t2) * 2];
            int c = ((int*)red)[(tid * 16 + t2) * 2 + 1];
            if (v < bv) { bv = v; bc = c; }
        }
        labels[(size_t)s * NN + pB + tid] = bc;
    }
}

// ---------------------------------------------------------------- fused kmeans update (upd1+upd2)
// One block per (c, s). Builds the ascending list of points with label c,
// then accumulates with the EXACT summation tree of the old kupd1/kupd2
// pair (per-256-chunk partial from 0.0f ascending i; chunk partials added
// ascending, empties add 0.0f) -> bitwise-identical centroids.
// Gather is batch-staged through LDS so global latency is parallel, not
// on the serial accumulate chain.
__global__ __launch_bounds__(256) void kupd12_k(const float* __restrict__ teacher,
                                                const int* __restrict__ labels,
                                                float* __restrict__ centT,
                                                float* __restrict__ cnorm) {
    const int c = blockIdx.x;
    const int s = blockIdx.y;
    const int t = threadIdx.x;
    __shared__ int list[NN];          // 32 KB: ascending matching point indices
    __shared__ float stage[UB * DD];  // 32 KB: gathered rows
    __shared__ int scan_s[256];
    __shared__ float red[256];
    __shared__ int total_s;

    const int* labS = labels + (size_t)s * NN;

    // count matches in this thread's 32-point stretch [32t, 32t+32)
    int my = 0;
#pragma unroll
    for (int j = 0; j < 32; j++) my += (labS[t * 32 + j] == c);
    scan_s[t] = my;
    __syncthreads();
    // inclusive prefix scan over 256 threads
    for (int off = 1; off < 256; off <<= 1) {
        int v = (t >= off) ? scan_s[t - off] : 0;
        __syncthreads();
        scan_s[t] += v;
        __syncthreads();
    }
    const int base = scan_s[t] - my;  // exclusive
    if (t == 255) total_s = scan_s[255];
    // ordered fill: stretches are ordered by t, within-stretch ascending
    int pos = base;
#pragma unroll
    for (int j = 0; j < 32; j++) {
        int p = t * 32 + j;
        if (labS[p] == c) list[pos++] = p;
    }
    __syncthreads();
    const int total = total_s;

    // batched gather + exact two-level tree sum
    float sum = 0.f, part = 0.f;
    int curb = 0;  // current 256-point chunk id (0..31)
    for (int g0 = 0; g0 < total; g0 += UB) {
        const int gn = (total - g0 < UB) ? (total - g0) : UB;
        __syncthreads();  // previous batch's stage reads complete
        // cooperative stage: rows list[g0..g0+gn) -> stage[j][*]; coalesced
        for (int u = t; u < gn * (DD / 4); u += 256) {
            int j = u >> 6;       // 64 float4 per row
            int col4 = (u & 63) << 2;
            *(float4*)&stage[j * DD + col4] =
                *(const float4*)&teacher[(size_t)list[g0 + j] * DD + col4];
        }
        __syncthreads();
        // ordered accumulate from LDS (uniform control flow, no global latency)
        for (int j = 0; j < gn; j++) {
            int p = list[g0 + j];  // LDS broadcast
            int b = p >> 8;
            while (curb < b) { sum += part; part = 0.f; curb++; }
            part += stage[j * DD + t];
        }
    }
    while (curb < 32) { sum += part; part = 0.f; curb++; }

    float old = centT[((size_t)s * DD + t) * CC + c];
    float nv = (total > 0) ? (sum / (float)total) : old;
    centT[((size_t)s * DD + t) * CC + c] = nv;
    red[t] = nv * nv;
    __syncthreads();
    for (int w = 128; w > 0; w >>= 1) {
        if (t < w) red[t] += red[t + w];
        __syncthreads();
    }
    if (t == 0) cnorm[s * CC + c] = red[0];
}

// ---------------------------------------------------------------- fused GEMM + per-row top-8 (per column split)
// BK=32 single-buffered, staged via global_load_lds DMA (no staging VGPRs,
// no per-thread load/store address VALU). __launch_bounds__(256,4) caps
// VGPR at 128 (need ~116, no spill) -> 4 waves/SIMD -> 4 blocks/CU; TLP
// across the 4 resident blocks hides the stage drain (round-8's 172-VGPR
// version was pinned at 2 blocks/CU -- the HW wave-slot quantum steps at
// 128). FMA chain per (row,col) still ascends k=0..255 in identical order
// -> bitwise-identical sums; scan/merge identical to the verified round-8.
__global__ __launch_bounds__(256, 4) void topk_gemm_k(const float* __restrict__ sT,
                                                      const float* __restrict__ tT,
                                                      float* __restrict__ pv,
                                                      int* __restrict__ pi) {
    __shared__ __attribute__((aligned(16))) float smem[BK * BM + BK * BN];  // 32 KB
    float* As = smem;            // [BK][BM] k-major
    float* Bs = smem + BK * BM;  // [BK][BN]

    const int split = blockIdx.x;
    const int rowB = blockIdx.y * BM;
    const int tid = threadIdx.x;
    const int tx = tid & 15;
    const int ty = tid >> 4;
    const int wid = tid >> 6;   // wave 0..3
    const int lane = tid & 63;
    const int sr = tid >> 1;  // scan row 0..127
    const int sh = tid & 1;   // scan half-of-64-cols

    float tv[TK];
    int ti[TK];
#pragma unroll
    for (int q = 0; q < TK; q++) { tv[q] = -INFINITY; ti[q] = 0x7fffffff; }

    const int colBase = split * (NN / CSPLIT);

    for (int ct = 0; ct < NN / CSPLIT; ct += BN) {
        const int colB = colBase + ct;
        float acc[8][8];
#pragma unroll
        for (int a = 0; a < 8; a++)
#pragma unroll
            for (int b = 0; b < 8; b++) acc[a][b] = 0.f;

        for (int kt = 0; kt < DD; kt += BK) {
            __syncthreads();  // previous compute/scan reads done, LDS free
            // DMA stage: each instr moves 1 KB = 2 rows (lane 0..31 -> kk0,
            // 32..63 -> kk0+1); LDS dest wave-uniform, HW adds lane*16.
#pragma unroll
            for (int j = 0; j < 4; j++) {
                const int kk0 = ((wid << 2) | j) << 1;  // 0,2,..,30 across waves
                const int krow = kt + kk0 + (lane >> 5);
                const int e4 = (lane & 31) << 2;
                const float* ga = sT + (size_t)krow * NN + rowB + e4;
                const float* gb = tT + (size_t)krow * NN + colB + e4;
                __builtin_amdgcn_global_load_lds(
                    (const __attribute__((address_space(1))) void*)ga,
                    (__attribute__((address_space(3))) void*)(As + kk0 * BM), 16, 0, 0);
                __builtin_amdgcn_global_load_lds(
                    (const __attribute__((address_space(1))) void*)gb,
                    (__attribute__((address_space(3))) void*)(Bs + kk0 * BN), 16, 0, 0);
            }
            __syncthreads();  // vmcnt(0) drain before barrier -> tiles ready
#pragma unroll
            for (int kk = 0; kk < BK; kk++) {
                float4 a0 = *(float4*)&As[kk * BM + 4 * ty];
                float4 a1 = *(float4*)&As[kk * BM + 64 + 4 * ty];
                float4 b0 = *(float4*)&Bs[kk * BN + 4 * tx];
                float4 b1 = *(float4*)&Bs[kk * BN + 64 + 4 * tx];
                float ar[8] = {a0.x, a0.y, a0.z, a0.w, a1.x, a1.y, a1.z, a1.w};
                float bc[8] = {b0.x, b0.y, b0.z, b0.w, b1.x, b1.y, b1.z, b1.w};
#pragma unroll
                for (int a = 0; a < 8; a++)
#pragma unroll
                    for (int b = 0; b < 8; b++)
                        acc[a][b] = fmaf(ar[a], bc[b], acc[a][b]);
            }
        }
        __syncthreads();
        // C-tile in two 128x64 halves: stage (swizzled, +diag) then scan
#pragma unroll
        for (int h = 0; h < 2; h++) {
#pragma unroll
            for (int a = 0; a < 8; a++) {
                int ra = (a < 4) ? (4 * ty + a) : (64 + 4 * ty + (a - 4));
                int grow = rowB + ra;
#pragma unroll
                for (int b2 = 0; b2 < 4; b2++) {
                    int cb2 = 4 * tx + b2;  // col within half (0..63)
                    float v = acc[a][h * 4 + b2];
                    if (grow == colB + h * 64 + cb2) v += 10.f;
                    smem[ra * 64 + (cb2 ^ (ra & 31))] = v;
                }
            }
            __syncthreads();
            // per-thread running top-8 over 32 of this half's 64 columns
#pragma unroll 4
            for (int c = 0; c < 32; c++) {
                int cb2 = sh * 32 + c;
                float v = smem[sr * 64 + (cb2 ^ (sr & 31))];
                int gcol = colB + h * 64 + cb2;
                if (kbetter(v, gcol, tv[TK - 1], ti[TK - 1])) {
                    tv[TK - 1] = v;
                    ti[TK - 1] = gcol;
#pragma unroll
                    for (int q = TK - 1; q > 0; --q) {
                        if (kbetter(tv[q], ti[q], tv[q - 1], ti[q - 1])) {
                            float t1 = tv[q]; tv[q] = tv[q - 1]; tv[q - 1] = t1;
                            int t2 = ti[q]; ti[q] = ti[q - 1]; ti[q - 1] = t2;
                        }
                    }
                }
            }
            __syncthreads();
        }
    }
    // merge the two threads of each row, write split-partial top-8
    float* mv = smem;                  // [128][2][8]
    int* mi = (int*)(smem + 2048);     // [128][2][8]
#pragma unroll
    for (int q = 0; q < TK; q++) {
        mv[(sr * 2 + sh) * TK + q] = tv[q];
        mi[(sr * 2 + sh) * TK + q] = ti[q];
    }
    __syncthreads();
    if (sh == 0) {
        int row = rowB + sr;
        unsigned used = 0;
        for (int o = 0; o < TK; o++) {
            float bv = -INFINITY;
            int bi = 0x7fffffff;
            int bsel = -1;
            for (int m = 0; m < 16; m++) {
                if ((used >> m) & 1u) continue;
                float v = mv[sr * 16 + m];
                int ix = mi[sr * 16 + m];
                if (bsel < 0 || kbetter(v, ix, bv, bi)) { bv = v; bi = ix; bsel = m; }
            }
            used |= 1u << bsel;
            pv[((size_t)row * CSPLIT + split) * TK + o] = bv;
            pi[((size_t)row * CSPLIT + split) * TK + o] = bi;
        }
    }
}

// ---------------------------------------------------------------- merge split partials -> final top-8
__global__ __launch_bounds__(256) void topk_merge_k(const float* __restrict__ pv,
                                                    const int* __restrict__ pi,
                                                    int* __restrict__ iknn,
                                                    float* __restrict__ dknn) {
    int row = blockIdx.x * 256 + threadIdx.x;
    if (row >= NN) return;
    unsigned long long used0 = 0, used1 = 0;  // CSPLIT*TK = 128 candidate slots
    for (int o = 0; o < TK; o++) {
        float bv = -INFINITY;
        int bi = 0x7fffffff;
        int bsel = -1;
        for (int m = 0; m < CSPLIT * TK; m++) {
            bool u = (m < 64) ? ((used0 >> m) & 1ull) : ((used1 >> (m - 64)) & 1ull);
            if (u) continue;
            float v = pv[(size_t)row * CSPLIT * TK + m];
            int ix = pi[(size_t)row * CSPLIT * TK + m];
            if (bsel < 0 || kbetter(v, ix, bv, bi)) { bv = v; bi = ix; bsel = m; }
        }
        if (bsel < 64) used0 |= 1ull << bsel; else used1 |= 1ull << (bsel - 64);
        iknn[row * TK + o] = bi;
        dknn[row * TK + o] = bv;
    }
}

// ---------------------------------------------------------------- epilogue: masks + output
__global__ __launch_bounds__(256) void out_k(const int* __restrict__ iknn,
                                             const float* __restrict__ dknn,
                                             const unsigned int* __restrict__ bm,
                                             const int* __restrict__ labels,
                                             float* __restrict__ out) {
    int t = blockIdx.x * 256 + threadIdx.x;  // 0..65535
    int row = t >> 3;
    int ki = iknn[t];
    unsigned code = (unsigned)row * NN + (unsigned)ki;
    bool adj = (bm[code >> 5] >> (code & 31)) & 1u;
    bool close = false;
#pragma unroll
    for (int s = 0; s < KSEED; s++)
        close |= (labels[s * NN + row] == labels[s * NN + ki]);
    out[t] = (float)ki;
    out[NN * TK + t] = (adj || close) ? 1.0f : 0.0f;
    out[2 * NN * TK + t] = dknn[t];
}

// ----------------------------------------------------------------
extern "C" void kernel_launch(void* const* d_in, const int* in_sizes, int n_in,
                              void* d_out, int out_size, void* d_ws, size_t ws_size,
                              hipStream_t stream) {
    (void)n_in; (void)out_size; (void)ws_size;
    const float* student = (const float*)d_in[0];
    const float* teacher = (const float*)d_in[1];
    const int* edge = (const int*)d_in[2];
    const int* initIdx = (const int*)d_in[3];
    const int E = in_sizes[2] / 2;

    char* ws = (char*)d_ws;
    size_t off = 0;
    auto alloc = [&](size_t bytes) -> char* {
        char* p = ws + off;
        off += (bytes + 255) & ~(size_t)255;
        return p;
    };
    unsigned int* bm = (unsigned int*)alloc((size_t)NN * NN / 8);        // 8 MB
    float* sT = (float*)alloc((size_t)NN * DD * 4);                      // 8 MB
    float* tT = (float*)alloc((size_t)NN * DD * 4);                      // 8 MB
    float* centT = (float*)alloc((size_t)KSEED * DD * CC * 4);
    float* cnorm = (float*)alloc((size_t)KSEED * CC * 4);
    int* labels = (int*)alloc((size_t)KSEED * NN * 4);
    float* pv = (float*)alloc((size_t)NN * CSPLIT * TK * 4);
    int* pi = (int*)alloc((size_t)NN * CSPLIT * TK * 4);
    int* iknn = (int*)alloc((size_t)NN * TK * 4);
    float* dknn = (float*)alloc((size_t)NN * TK * 4);
    float* out = (float*)d_out;

    hipMemsetAsync(bm, 0, (size_t)NN * NN / 8, stream);
    adj_k<<<dim3((E + 255) / 256), 256, 0, stream>>>(edge, edge + E, bm, E);
    transpose_k<<<dim3(NN / 32, DD / 32), dim3(32, 8), 0, stream>>>(student, sT);
    transpose_k<<<dim3(NN / 32, DD / 32), dim3(32, 8), 0, stream>>>(teacher, tT);

    kinit_k<<<dim3(CC, KSEED), 256, 0, stream>>>(teacher, initIdx, centT, cnorm);
    for (int it = 0; it < NITERS; ++it) {
        kassign_k<<<dim3(NN / 64, KSEED), 256, 0, stream>>>(tT, centT, cnorm, labels);
        kupd12_k<<<dim3(CC, KSEED), 256, 0, stream>>>(teacher, labels, centT, cnorm);
    }
    kassign_k<<<dim3(NN / 64, KSEED), 256, 0, stream>>>(tT, centT, cnorm, labels);

    topk_gemm_k<<<dim3(CSPLIT, NN / BM), 256, 0, stream>>>(sT, tT, pv, pi);
    topk_merge_k<<<dim3((NN + 255) / 256), 256, 0, stream>>>(pv, pi, iknn, dknn);
    out_k<<<dim3(NN * TK / 256), 256, 0, stream>>>(iknn, dknn, bm, labels, out);
}